// Round 14
// baseline (661.783 us; speedup 1.0000x reference)
//
#include <hip/hip_runtime.h>
#include <hip/hip_bf16.h>
#include <cstdint>
#include <cstddef>

#define B_ 512
#define L_ 192
#define D_ 256
#define H_ 4
#define DH_ 64
#define FF_ 1024
#define NL_ 2
#define LP_ 30
#define LNEG_ 300
#define NF_ 13
#define M_ (B_*L_)   // 98304 tokens
#define NT_ 330      // LP_+LNEG_
#define V_ 30000

typedef __attribute__((ext_vector_type(8))) short bf16x8;
typedef __attribute__((ext_vector_type(4))) float f32x4;

// RNE float -> bf16 bits (finite inputs only)
__device__ __forceinline__ ushort f2b(float f) {
  union { float f; uint32_t u; } v; v.f = f;
  uint32_t u = v.u;
  return (ushort)((u + 0x7FFFu + ((u >> 16) & 1u)) >> 16);
}
__device__ __forceinline__ float b2f(ushort u) {
  union { uint32_t u; float f; } v; v.u = (uint32_t)u << 16; return v.f;
}
__device__ __forceinline__ void stage16(const ushort* src, char* dst) {
  __builtin_amdgcn_global_load_lds((const __attribute__((address_space(1))) unsigned int*)src,
                                   (__attribute__((address_space(3))) unsigned int*)dst, 16, 0, 0);
}

// ---------------- prefix sums of lens: off[513], per-chunk counts ----------------
__global__ __launch_bounds__(512) void k_prefix(
    const int* __restrict__ lens, int* __restrict__ off,
    int* __restrict__ ccnt, int* __restrict__ ccntp, int Bc, int nchunks)
{
  const int t = threadIdx.x;
  int s = 0;
  for (int i = 0; i < t; ++i) s += lens[i];
  off[t] = s;
  if (t == 511) off[512] = s + lens[511];
  if (t < nchunks) {
    int s2 = 0;
    const int c0 = t * Bc;
    for (int i = 0; i < Bc; ++i) s2 += lens[c0 + i];
    ccnt[t]  = s2;
    ccntp[t] = (s2 + 127) & ~127;
  }
}

// ---------------- generic fp32 -> bf16 conversion (2048 elems/block) ----------------
__global__ __launch_bounds__(256) void k_f2b(const float* __restrict__ in, ushort* __restrict__ out) {
  const int i = (blockIdx.x*256 + threadIdx.x)*8;
  float4 a = *(const float4*)(in+i);
  float4 b = *(const float4*)(in+i+4);
  ushort4 o1; o1.x=f2b(a.x); o1.y=f2b(a.y); o1.z=f2b(a.z); o1.w=f2b(a.w);
  ushort4 o2; o2.x=f2b(b.x); o2.y=f2b(b.y); o2.z=f2b(b.z); o2.w=f2b(b.w);
  *(ushort4*)(out+i)   = o1;
  *(ushort4*)(out+i+4) = o2;
}

// ---------------- weight conversion, all 4 groups in one launch ----------------
__global__ __launch_bounds__(256) void k_f2b4(
    const float* __restrict__ wq, const float* __restrict__ wo,
    const float* __restrict__ w1, const float* __restrict__ w2,
    ushort* __restrict__ oq, ushort* __restrict__ oo,
    ushort* __restrict__ o1, ushort* __restrict__ o2)
{
  int bb = blockIdx.x;
  const float* in; ushort* out; int base;
  if (bb < 192)      { in = wq; out = oq; base = bb; }
  else if (bb < 256) { in = wo; out = oo; base = bb - 192; }
  else if (bb < 512) { in = w1; out = o1; base = bb - 256; }
  else               { in = w2; out = o2; base = bb - 512; }
  const int i = base*2048 + threadIdx.x*8;
  float4 a = *(const float4*)(in+i);
  float4 b = *(const float4*)(in+i+4);
  ushort4 q1; q1.x=f2b(a.x); q1.y=f2b(a.y); q1.z=f2b(a.z); q1.w=f2b(a.w);
  ushort4 q2; q2.x=f2b(b.x); q2.y=f2b(b.y); q2.z=f2b(b.z); q2.w=f2b(b.w);
  *(ushort4*)(out+i)   = q1;
  *(ushort4*)(out+i+4) = q2;
}

// ---------------- embedding gather into COMPACT token space (bf16 state only) ----------------
__global__ __launch_bounds__(256) void k_embed(
    const int* __restrict__ attr, const int* __restrict__ inds,
    const int* __restrict__ lens, const int* __restrict__ off,
    const float* __restrict__ attr_emb, const float* __restrict__ ind_emb,
    ushort* __restrict__ xb)
{
  int idx = blockIdx.x*256 + threadIdx.x;
  int token = idx >> 6;
  int c = (idx & 63) * 4;
  int b = token / L_;
  int l = token - b*L_;
  if (l >= lens[b]) return;
  size_t crow = (size_t)off[b] + l;
  int a = attr[token];
  int id = inds[token];
  const float4 e  = *(const float4*)(attr_emb + (size_t)a*D_ + c);
  const float4 ie = *(const float4*)(ind_emb  + (size_t)id*D_ + c);
  ushort4 ob; ob.x=f2b(e.x+ie.x); ob.y=f2b(e.y+ie.y); ob.z=f2b(e.z+ie.z); ob.w=f2b(e.w+ie.w);
  *(ushort4*)(xb + crow*D_ + c) = ob;
}

// ---------------- bf16 MFMA GEMM (128x128), swizzled LDS, SWAPPED operands ----------------
template<int OUT_BF16, int RELU>
__global__ __launch_bounds__(256) void k_gemm_mfma(
    const ushort* __restrict__ A, const int* __restrict__ aoffp,
    const int* __restrict__ cntp,
    const ushort* __restrict__ W, const float* __restrict__ bias,
    void* __restrict__ Cv, int N, int K)
{
  if ((int)blockIdx.y * 128 >= *cntp) return;
  __shared__ alignas(16) ushort As[8192];
  __shared__ alignas(16) ushort Bs[8192];
  const int abase = *aoffp;
  const int tid = threadIdx.x;
  const int w = tid >> 6, l = tid & 63;
  const int g = l >> 4, c16 = l & 15;
  const int m0 = blockIdx.y*128, n0 = blockIdx.x*128;
  const int wr = w >> 1, wc = w & 1;
  const int swzr = (c16 & 7) << 4;

  f32x4 acc[4][4];
  #pragma unroll
  for (int i=0;i<4;++i)
    #pragma unroll
    for (int j=0;j<4;++j) acc[i][j] = (f32x4){0.f,0.f,0.f,0.f};

  for (int k0=0; k0<K; k0+=64) {
    #pragma unroll
    for (int i=0;i<4;++i) {
      const int li  = i*4096 + tid*16;
      const int row = li >> 7;
      const int col = ((li & 127) ^ ((row & 7) << 4)) >> 1;
      stage16(A + (size_t)(abase+m0+row)*K + k0 + col, (char*)(As) + i*4096 + w*1024);
      stage16(W + (size_t)(n0+row)*K + k0 + col,       (char*)(Bs) + i*4096 + w*1024);
    }
    __syncthreads();
    #pragma unroll
    for (int ks=0; ks<2; ++ks) {
      const int cb = ((g*16 + ks*64) ^ swzr) >> 1;
      bf16x8 af[4], bfr[4];
      #pragma unroll
      for (int i2=0;i2<4;++i2) {
        af[i2]  = *(const bf16x8*)(As + (size_t)(wr*64 + i2*16 + c16)*64 + cb);
        bfr[i2] = *(const bf16x8*)(Bs + (size_t)(wc*64 + i2*16 + c16)*64 + cb);
      }
      #pragma unroll
      for (int mi=0;mi<4;++mi)
        #pragma unroll
        for (int ni=0;ni<4;++ni)
          acc[mi][ni] = __builtin_amdgcn_mfma_f32_16x16x32_bf16(bfr[ni], af[mi], acc[mi][ni], 0,0,0);
    }
    __syncthreads();
  }
  #pragma unroll
  for (int ni=0;ni<4;++ni) {
    const int nc = n0 + wc*64 + ni*16 + 4*g;
    const float4 bv = *(const float4*)(bias + nc);
    #pragma unroll
    for (int mi=0;mi<4;++mi) {
      float v0 = acc[mi][ni][0] + bv.x;
      float v1 = acc[mi][ni][1] + bv.y;
      float v2 = acc[mi][ni][2] + bv.z;
      float v3 = acc[mi][ni][3] + bv.w;
      if (RELU) { v0=fmaxf(v0,0.f); v1=fmaxf(v1,0.f); v2=fmaxf(v2,0.f); v3=fmaxf(v3,0.f); }
      const size_t idx = (size_t)(m0 + wr*64 + mi*16 + c16)*N + nc;
      if (OUT_BF16) {
        ushort4 o; o.x=f2b(v0); o.y=f2b(v1); o.z=f2b(v2); o.w=f2b(v3);
        *(ushort4*)((ushort*)Cv + idx) = o;
      } else {
        float4 o; o.x=v0; o.y=v1; o.z=v2; o.w=v3;
        *(float4*)((float*)Cv + idx) = o;
      }
    }
  }
}

// ---------------- fused GEMM(N=256) + residual + LN, bf16 state, swizzled, SWAPPED ----------------
__global__ __launch_bounds__(512) void k_gemm_ln(
    const ushort* __restrict__ A,
    const int* __restrict__ cntp, const int* __restrict__ cnt,
    const int* __restrict__ xoffp,
    const ushort* __restrict__ W,
    const float* __restrict__ bias,
    const float* __restrict__ lns, const float* __restrict__ lnb,
    ushort* __restrict__ xb, int K)
{
  const int m0 = blockIdx.x*128;
  if (m0 >= *cntp) return;
  __shared__ alignas(16) ushort As[8192];
  __shared__ alignas(16) ushort Bs[16384];
  __shared__ float red[4][2][128];
  const int tid = threadIdx.x;
  const int w = tid >> 6, l = tid & 63;
  const int g = l >> 4, c16 = l & 15;
  const int wr = w >> 2, wc = w & 3;
  const int swzr = (c16 & 7) << 4;

  f32x4 acc[4][4];
  #pragma unroll
  for (int i=0;i<4;++i)
    #pragma unroll
    for (int j=0;j<4;++j) acc[i][j] = (f32x4){0.f,0.f,0.f,0.f};

  for (int k0=0; k0<K; k0+=64) {
    #pragma unroll
    for (int i=0;i<2;++i) {
      const int li  = i*8192 + tid*16;
      const int row = li >> 7;
      const int col = ((li & 127) ^ ((row & 7) << 4)) >> 1;
      stage16(A + (size_t)(m0+row)*K + k0 + col, (char*)(As) + i*8192 + w*1024);
    }
    #pragma unroll
    for (int i=0;i<4;++i) {
      const int li  = i*8192 + tid*16;
      const int row = li >> 7;
      const int col = ((li & 127) ^ ((row & 7) << 4)) >> 1;
      stage16(W + (size_t)row*K + k0 + col, (char*)(Bs) + i*8192 + w*1024);
    }
    __syncthreads();
    #pragma unroll
    for (int ks=0; ks<2; ++ks) {
      const int cb = ((g*16 + ks*64) ^ swzr) >> 1;
      bf16x8 af[4], bfr[4];
      #pragma unroll
      for (int i2=0;i2<4;++i2) {
        af[i2]  = *(const bf16x8*)(As + (size_t)(wr*64 + i2*16 + c16)*64 + cb);
        bfr[i2] = *(const bf16x8*)(Bs + (size_t)(wc*64 + i2*16 + c16)*64 + cb);
      }
      #pragma unroll
      for (int mi=0;mi<4;++mi)
        #pragma unroll
        for (int ni=0;ni<4;++ni)
          acc[mi][ni] = __builtin_amdgcn_mfma_f32_16x16x32_bf16(bfr[ni], af[mi], acc[mi][ni], 0,0,0);
    }
    __syncthreads();
  }

  const int xbase = *xoffp + m0;
  float4 bv[4], sv[4], bb[4];
  #pragma unroll
  for (int ni=0;ni<4;++ni) {
    const int nc = wc*64 + ni*16 + 4*g;
    bv[ni] = *(const float4*)(bias + nc);
    sv[ni] = *(const float4*)(lns + nc);
    bb[ni] = *(const float4*)(lnb + nc);
  }
  float ps[4], pq[4];
  #pragma unroll
  for (int mi=0;mi<4;++mi) {
    ps[mi]=0.f; pq[mi]=0.f;
    const int lrow = wr*64 + mi*16 + c16;
    const ushort* xr = xb + (size_t)(xbase + lrow)*256;
    #pragma unroll
    for (int ni=0;ni<4;++ni) {
      const int nc = wc*64 + ni*16 + 4*g;
      ushort4 rx = *(const ushort4*)(xr + nc);
      float y0 = acc[mi][ni][0] + bv[ni].x + b2f(rx.x);
      float y1 = acc[mi][ni][1] + bv[ni].y + b2f(rx.y);
      float y2 = acc[mi][ni][2] + bv[ni].z + b2f(rx.z);
      float y3 = acc[mi][ni][3] + bv[ni].w + b2f(rx.w);
      acc[mi][ni][0]=y0; acc[mi][ni][1]=y1; acc[mi][ni][2]=y2; acc[mi][ni][3]=y3;
      ps[mi] += (y0+y1)+(y2+y3);
      pq[mi] += (y0*y0+y1*y1)+(y2*y2+y3*y3);
    }
  }
  #pragma unroll
  for (int mi=0;mi<4;++mi) {
    ps[mi] += __shfl_xor(ps[mi], 16, 64);
    pq[mi] += __shfl_xor(pq[mi], 16, 64);
    ps[mi] += __shfl_xor(ps[mi], 32, 64);
    pq[mi] += __shfl_xor(pq[mi], 32, 64);
  }
  if (g == 0) {
    #pragma unroll
    for (int mi=0;mi<4;++mi) {
      const int lrow = wr*64 + mi*16 + c16;
      red[wc][0][lrow] = ps[mi];
      red[wc][1][lrow] = pq[mi];
    }
  }
  __syncthreads();
  const int cexact = *cnt;
  #pragma unroll
  for (int mi=0;mi<4;++mi) {
    const int lrow = wr*64 + mi*16 + c16;
    float tsum = red[0][0][lrow] + red[1][0][lrow] + red[2][0][lrow] + red[3][0][lrow];
    float tsq  = red[0][1][lrow] + red[1][1][lrow] + red[2][1][lrow] + red[3][1][lrow];
    float mean = tsum * (1.f/256.f);
    float var  = tsq * (1.f/256.f) - mean*mean;
    float inv  = rsqrtf(var + 1e-5f);
    if (m0 + lrow < cexact) {
      ushort* xbr = xb + (size_t)(xbase + lrow)*256;
      #pragma unroll
      for (int ni=0;ni<4;++ni) {
        const int nc = wc*64 + ni*16 + 4*g;
        ushort4 o;
        o.x = f2b((acc[mi][ni][0]-mean)*inv*sv[ni].x + bb[ni].x);
        o.y = f2b((acc[mi][ni][1]-mean)*inv*sv[ni].y + bb[ni].y);
        o.z = f2b((acc[mi][ni][2]-mean)*inv*sv[ni].z + bb[ni].z);
        o.w = f2b((acc[mi][ni][3]-mean)*inv*sv[ni].w + bb[ni].w);
        *(ushort4*)(xbr + nc) = o;
      }
    }
  }
}

// ---------------- fused FFN v6: 64 tok/block, X in REGISTERS, 2x16KB W ping-pong, 48KB LDS (3 blk/CU) ----------------
// 512 thr = 8 waves (wr=w>>2 in {0,1}; wc=w&3). 64 chunks: c=s*8+q; q<4 -> W1[kc=q], q>=4 -> W2[t2=q-4].
// Prologue: stage X(32KB) over W region -> regs (16 bf16x8/thread) -> region recycled for W ping-pong.
// Step: prefetch chunk q+1 into nxt buf -> compute chunk q from cur buf -> __syncthreads.
// LDS 48KB: Wb 2x16KB [0,32K) | Hs[64tok][256B] swz [32K,48K). red aliases Wb post-loop.
__global__ __launch_bounds__(512) void k_ffn(
    const int* __restrict__ cntp, const int* __restrict__ cnt,
    const int* __restrict__ xoffp,
    const ushort* __restrict__ W1, const float* __restrict__ b1,
    const ushort* __restrict__ W2, const float* __restrict__ b2,
    const float* __restrict__ lns, const float* __restrict__ lnb,
    ushort* __restrict__ xb)
{
  const int m0 = blockIdx.x*64;
  if (m0 >= *cntp) return;
  __shared__ alignas(16) char lds[49152];
  char* Wb = lds;                       // [0, 32768): 2 x 16KB (X staging overlays at prologue)
  char* Hs = lds + 32768;               // [32768, 49152)
  float* red = (float*)lds;             // aliases Wb after main loop
  const int tid = threadIdx.x;
  const int w = tid >> 6, l = tid & 63;
  const int g = l >> 4, c16 = l & 15;
  const int wr = w >> 2, wc = w & 3;
  const int swzr = (c16 & 7) << 4;
  const int xbase = *xoffp + m0;

  int tokl[2];
  #pragma unroll
  for (int mi=0;mi<2;++mi) tokl[mi] = wr*32 + mi*16 + c16;

  // chunk stager: q<4 -> W1(slice s, kcol q); q>=4 -> W2(dout half (q-4)>>1, ffcol s*128+((q-4)&1)*64)
  auto stage_chunk = [&](int s, int q, char* dst) {
    #pragma unroll
    for (int i=0;i<2;++i) {
      const int li = i*8192 + tid*16;
      const int row = li >> 7;
      const int colb = (li & 127) ^ ((row & 7) << 4);
      const ushort* src;
      if (q < 4) src = W1 + (size_t)(s*128+row)*256 + q*64 + (colb>>1);
      else {
        const int t2 = q - 4;
        src = W2 + (size_t)((t2>>1)*128+row)*1024 + s*128 + (t2&1)*64 + (colb>>1);
      }
      stage16(src, dst + i*8192 + w*1024);
    }
  };

  // ---- prologue: stage X (32KB, overlays Wb), read to registers, then recycle for W ----
  #pragma unroll
  for (int i=0;i<4;++i) {
    const int li = i*8192 + tid*16;
    const int row = li >> 9;                       // 512B per token row
    const int colb = (li & 511) ^ ((row & 7) << 4);
    stage16(xb + (size_t)(xbase+row)*256 + (colb>>1), lds + i*8192 + w*1024);
  }
  __syncthreads();
  bf16x8 xreg[2][8];                               // [token row][k-frag f: k = f*32 + g*8 ..]
  #pragma unroll
  for (int mi=0;mi<2;++mi)
    #pragma unroll
    for (int f=0;f<8;++f)
      xreg[mi][f] = *(const bf16x8*)(lds + tokl[mi]*512 + ((f*64 + g*16) ^ swzr));
  __syncthreads();                                 // all X reads done before W overwrites
  stage_chunk(0, 0, Wb);
  __syncthreads();                                 // chunk 0 resident

  f32x4 tac[2][4];
  #pragma unroll
  for (int i=0;i<2;++i)
    #pragma unroll
    for (int j=0;j<4;++j) tac[i][j] = (f32x4){0.f,0.f,0.f,0.f};

  int pp = 0;
  for (int s=0; s<8; ++s) {
    f32x4 hac[2][2];
    #pragma unroll
    for (int i=0;i<2;++i)
      #pragma unroll
      for (int j=0;j<2;++j) hac[i][j] = (f32x4){0.f,0.f,0.f,0.f};

    #pragma unroll
    for (int q=0; q<8; ++q) {
      // prefetch chunk q+1 (or next slice's chunk 0) into the other buffer
      if (q < 7)      stage_chunk(s, q+1, Wb + (pp^1)*16384);
      else if (s < 7) stage_chunk(s+1, 0, Wb + (pp^1)*16384);
      char* curbuf = Wb + pp*16384;

      if (q < 4) {
        // ---- W1 chunk kc=q: h += W1 @ X(regs) ----
        #pragma unroll
        for (int ks=0; ks<2; ++ks) {
          const int cbw = (ks*64 + g*16) ^ swzr;
          bf16x8 w1f[2];
          #pragma unroll
          for (int ni=0;ni<2;++ni)
            w1f[ni] = *(const bf16x8*)(curbuf + (wc*32 + ni*16 + c16)*128 + cbw);
          #pragma unroll
          for (int mi=0;mi<2;++mi)
            #pragma unroll
            for (int ni=0;ni<2;++ni)
              hac[mi][ni] = __builtin_amdgcn_mfma_f32_16x16x32_bf16(w1f[ni], xreg[mi][q*2+ks], hac[mi][ni], 0,0,0);
        }
        if (q == 3) {              // bias+relu -> Hs (ushort4, swizzled by token row)
          #pragma unroll
          for (int ni=0;ni<2;++ni) {
            const int ffc = wc*32 + ni*16 + 4*g;
            const float4 bb1 = *(const float4*)(b1 + s*128 + ffc);
            #pragma unroll
            for (int mi=0;mi<2;++mi) {
              ushort4 o;
              o.x = f2b(fmaxf(hac[mi][ni][0] + bb1.x, 0.f));
              o.y = f2b(fmaxf(hac[mi][ni][1] + bb1.y, 0.f));
              o.z = f2b(fmaxf(hac[mi][ni][2] + bb1.z, 0.f));
              o.w = f2b(fmaxf(hac[mi][ni][3] + bb1.w, 0.f));
              *(ushort4*)(Hs + tokl[mi]*256 + ((ffc*2) ^ swzr)) = o;
            }
          }
        }
      } else {
        // ---- W2 chunk t2=q-4 (dh=t2>>1, kc2=t2&1): t[dh] += W2 @ h ----
        const int dh = (q-4) >> 1, kc2 = (q-4) & 1;
        #pragma unroll
        for (int ks=0; ks<2; ++ks) {
          const int cbw = (ks*64 + g*16) ^ swzr;
          bf16x8 w2f[2], hf[2];
          #pragma unroll
          for (int ni=0;ni<2;++ni)
            w2f[ni] = *(const bf16x8*)(curbuf + (wc*32 + ni*16 + c16)*128 + cbw);
          #pragma unroll
          for (int mi=0;mi<2;++mi)
            hf[mi] = *(const bf16x8*)(Hs + tokl[mi]*256 + ((kc2*128 + ks*64 + g*16) ^ swzr));
          #pragma unroll
          for (int mi=0;mi<2;++mi)
            #pragma unroll
            for (int ni=0;ni<2;++ni)
              tac[mi][dh*2+ni] = __builtin_amdgcn_mfma_f32_16x16x32_bf16(w2f[ni], hf[mi], tac[mi][dh*2+ni], 0,0,0);
        }
      }
      __syncthreads();
      pp ^= 1;
    }
  }

  // ---- epilogue: y = t + b2 + resid; LN over 256; write xb. col(n) = (n>>1)*128 + wc*32 + (n&1)*16 + 4g ----
  float4 bv[4], sv[4], bb[4];
  #pragma unroll
  for (int n=0;n<4;++n) {
    const int nc = (n>>1)*128 + wc*32 + (n&1)*16 + 4*g;
    bv[n] = *(const float4*)(b2 + nc);
    sv[n] = *(const float4*)(lns + nc);
    bb[n] = *(const float4*)(lnb + nc);
  }
  float ps[2], pq[2];
  #pragma unroll
  for (int mi=0;mi<2;++mi) {
    ps[mi]=0.f; pq[mi]=0.f;
    const ushort* xr = xb + (size_t)(xbase + tokl[mi])*256;
    #pragma unroll
    for (int n=0;n<4;++n) {
      const int nc = (n>>1)*128 + wc*32 + (n&1)*16 + 4*g;
      ushort4 rx = *(const ushort4*)(xr + nc);
      float y0 = tac[mi][n][0] + bv[n].x + b2f(rx.x);
      float y1 = tac[mi][n][1] + bv[n].y + b2f(rx.y);
      float y2 = tac[mi][n][2] + bv[n].z + b2f(rx.z);
      float y3 = tac[mi][n][3] + bv[n].w + b2f(rx.w);
      tac[mi][n][0]=y0; tac[mi][n][1]=y1; tac[mi][n][2]=y2; tac[mi][n][3]=y3;
      ps[mi] += (y0+y1)+(y2+y3);
      pq[mi] += (y0*y0+y1*y1)+(y2*y2+y3*y3);
    }
  }
  #pragma unroll
  for (int mi=0;mi<2;++mi) {
    ps[mi] += __shfl_xor(ps[mi], 16, 64);
    pq[mi] += __shfl_xor(pq[mi], 16, 64);
    ps[mi] += __shfl_xor(ps[mi], 32, 64);
    pq[mi] += __shfl_xor(pq[mi], 32, 64);
  }
  if (g == 0) {
    #pragma unroll
    for (int mi=0;mi<2;++mi) {
      red[(wc*2+0)*64 + tokl[mi]] = ps[mi];
      red[(wc*2+1)*64 + tokl[mi]] = pq[mi];
    }
  }
  __syncthreads();
  const int cexact = *cnt;
  #pragma unroll
  for (int mi=0;mi<2;++mi) {
    const int lrow = tokl[mi];
    float tsum = red[0*64+lrow] + red[2*64+lrow] + red[4*64+lrow] + red[6*64+lrow];
    float tsq  = red[1*64+lrow] + red[3*64+lrow] + red[5*64+lrow] + red[7*64+lrow];
    float mean = tsum * (1.f/256.f);
    float var  = tsq * (1.f/256.f) - mean*mean;
    float inv  = rsqrtf(var + 1e-5f);
    if (m0 + lrow < cexact) {
      ushort* xbr = xb + (size_t)(xbase + lrow)*256;
      #pragma unroll
      for (int n=0;n<4;++n) {
        const int nc = (n>>1)*128 + wc*32 + (n&1)*16 + 4*g;
        ushort4 o;
        o.x = f2b((tac[mi][n][0]-mean)*inv*sv[n].x + bb[n].x);
        o.y = f2b((tac[mi][n][1]-mean)*inv*sv[n].y + bb[n].y);
        o.z = f2b((tac[mi][n][2]-mean)*inv*sv[n].z + bb[n].z);
        o.w = f2b((tac[mi][n][3]-mean)*inv*sv[n].w + bb[n].w);
        *(ushort4*)(xbr + nc) = o;
      }
    }
  }
}

// ---------------- MFMA flash attention on compact rows: block per (b,h) ----------------
__global__ __launch_bounds__(256) void k_attn_mfma(
    const ushort* __restrict__ qkv, ushort* __restrict__ ctx,
    const int* __restrict__ offc)
{
  __shared__ alignas(16) char lds[81920];
  char* Kb = lds;
  char* Vt = lds + 24576;
  const int tid = threadIdx.x;
  const int w = tid >> 6, l = tid & 63;
  const int g = l >> 4, c = l & 15;
  char* Pw = lds + 57344 + w*6144;
  const int bl = blockIdx.x >> 2, h = blockIdx.x & 3;
  const int rowbase = offc[bl] - offc[0];
  const int len = offc[bl+1] - offc[bl];
  const int nkt = (len + 15) >> 4;
  const int nkf = (len + 31) >> 5;
  const ushort* base = qkv + (size_t)rowbase*768;
  ushort* cbase = ctx + (size_t)rowbase*256;

  const int lenk8 = nkt*16*8;
  for (int idx = tid; idx < lenk8; idx += 256) {
    int row = idx >> 3, ch = idx & 7;
    uint4 v = *(const uint4*)(base + (size_t)row*768 + 256 + h*64 + ch*8);
    *(uint4*)(Kb + ((row*128 + ch*16) ^ ((row&7)<<4))) = v;
  }
  {
    const int lenv = nkf*32;
    int d0 = (tid & 15)*4;
    for (int key = tid >> 4; key < lenv; key += 16) {
      ushort4 v = *(const ushort4*)(base + (size_t)key*768 + 512 + h*64 + d0);
      ushort vv[4] = {v.x, v.y, v.z, v.w};
      #pragma unroll
      for (int j=0;j<4;++j) {
        int d = d0 + j;
        *(ushort*)(Vt + ((d*512 + key*2) ^ ((d&7)<<4))) = vv[j];
      }
    }
  }
  __syncthreads();

  for (int t = nkt; t < 2*nkf; ++t) {
    #pragma unroll
    for (int r=0;r<4;++r) {
      int q = 4*g + r;
      *(ushort*)(Pw + (((t>>1)*1024 + q*64 + ((t&1)*16 + c)*2) ^ (((q>>2)&3)<<4))) = 0;
    }
  }

  const int nst = (len + 15) >> 4;
  for (int s = w; s < nst; s += 4) {
    const ushort* qp = base + (size_t)(s*16 + c)*768 + h*64 + g*8;
    bf16x8 aq0 = *(const bf16x8*)qp;
    bf16x8 aq1 = *(const bf16x8*)(qp + 32);

    f32x4 sc[12];
    #pragma unroll
    for (int t=0;t<12;++t) {
      sc[t] = (f32x4){0.f,0.f,0.f,0.f};
      if (t < nkt) {
        int ba0 = ((t*16 + c)*128 + g*16)      ^ ((c&7)<<4);
        int ba1 = ((t*16 + c)*128 + g*16 + 64) ^ ((c&7)<<4);
        bf16x8 k0 = *(const bf16x8*)(Kb + ba0);
        bf16x8 k1 = *(const bf16x8*)(Kb + ba1);
        sc[t] = __builtin_amdgcn_mfma_f32_16x16x32_bf16(aq0, k0, sc[t], 0,0,0);
        sc[t] = __builtin_amdgcn_mfma_f32_16x16x32_bf16(aq1, k1, sc[t], 0,0,0);
        if (t == nkt-1 && t*16 + c >= len)
          sc[t] = (f32x4){-1e30f,-1e30f,-1e30f,-1e30f};
      }
    }
    float mr[4] = {-1e30f,-1e30f,-1e30f,-1e30f};
    #pragma unroll
    for (int t=0;t<12;++t) if (t<nkt) {
      #pragma unroll
      for (int r=0;r<4;++r) mr[r] = fmaxf(mr[r], sc[t][r]);
    }
    #pragma unroll
    for (int r=0;r<4;++r) {
      mr[r] = fmaxf(mr[r], __shfl_xor(mr[r], 1, 16));
      mr[r] = fmaxf(mr[r], __shfl_xor(mr[r], 2, 16));
      mr[r] = fmaxf(mr[r], __shfl_xor(mr[r], 4, 16));
      mr[r] = fmaxf(mr[r], __shfl_xor(mr[r], 8, 16));
    }
    float sr[4] = {0.f,0.f,0.f,0.f};
    #pragma unroll
    for (int t=0;t<12;++t) if (t<nkt) {
      #pragma unroll
      for (int r=0;r<4;++r) {
        float p = __expf((sc[t][r] - mr[r]) * 0.125f);
        sr[r] += p;
        int q = 4*g + r;
        *(ushort*)(Pw + (((t>>1)*1024 + q*64 + ((t&1)*16 + c)*2) ^ (((q>>2)&3)<<4))) = f2b(p);
      }
    }
    #pragma unroll
    for (int r=0;r<4;++r) {
      sr[r] += __shfl_xor(sr[r], 1, 16);
      sr[r] += __shfl_xor(sr[r], 2, 16);
      sr[r] += __shfl_xor(sr[r], 4, 16);
      sr[r] += __shfl_xor(sr[r], 8, 16);
    }
    f32x4 oa[4];
    #pragma unroll
    for (int dt=0;dt<4;++dt) oa[dt] = (f32x4){0.f,0.f,0.f,0.f};
    #pragma unroll
    for (int kf=0;kf<6;++kf) if (kf<nkf) {
      bf16x8 pf = *(const bf16x8*)(Pw + ((kf*1024 + c*64 + g*16) ^ (((c>>2)&3)<<4)));
      #pragma unroll
      for (int dt=0;dt<4;++dt) {
        int d = dt*16 + c;
        bf16x8 vf = *(const bf16x8*)(Vt + ((d*512 + kf*64 + g*16) ^ ((d&7)<<4)));
        oa[dt] = __builtin_amdgcn_mfma_f32_16x16x32_bf16(pf, vf, oa[dt], 0,0,0);
      }
    }
    float inv[4];
    #pragma unroll
    for (int r=0;r<4;++r) inv[r] = 1.f / sr[r];
    ushort* orow = cbase + (size_t)(s*16)*256 + h*64;
    #pragma unroll
    for (int r=0;r<4;++r) {
      int q = 4*g + r;
      if (s*16 + q < len) {
        #pragma unroll
        for (int dt=0;dt<4;++dt)
          orow[(size_t)q*256 + dt*16 + c] = f2b(oa[dt][r] * inv[r]);
      }
    }
  }
}

// ---------------- ragged weighted pooling (compact bf16 x) + concat id embeddings ----------------
__global__ __launch_bounds__(256) void k_pool(
    const ushort* __restrict__ xb, const int* __restrict__ off,
    const float* __restrict__ attr_tf, const float* __restrict__ attr_feat,
    const int* __restrict__ lens_u, const int* __restrict__ lens_i,
    const int* __restrict__ user_ids, const int* __restrict__ item_ids,
    const float* __restrict__ user_tab, const float* __restrict__ item_tab,
    const float* __restrict__ feat_w, const float* __restrict__ feat_b,
    float* __restrict__ user_out, float* __restrict__ item_out)
{
  __shared__ float wu[L_], tf[L_];
  const int b = blockIdx.x;
  const int t = threadIdx.x;
  if (t < L_) {
    const float* f = attr_feat + ((size_t)b*L_ + t)*NF_;
    float sacc = feat_b[0];
    #pragma unroll
    for (int j=0;j<NF_;++j) sacc = fmaf(f[j], feat_w[j], sacc);
    wu[t] = 1.f/(1.f+__expf(-sacc));
    tf[t] = attr_tf[b*L_+t];
  }
  __syncthreads();
  const int Lu = lens_u[b], Li = lens_i[b];
  const ushort* xrow = xb + (size_t)off[b]*D_;
  float su=0.f, si=0.f;
  for (int l=0;l<Lu+Li;++l) {
    float val = b2f(xrow[(size_t)l*D_ + t]) * tf[l];
    if (l < Lu) su = fmaf(val, wu[l], su);
    else        si = fmaf(val, 1.f-wu[l], si);
  }
  user_out[(size_t)b*512 + t]       = su/(float)Lu;
  item_out[(size_t)b*512 + t]       = si/(float)Li;
  user_out[(size_t)b*512 + 256 + t] = user_tab[(size_t)user_ids[b]*D_ + t];
  item_out[(size_t)b*512 + 256 + t] = item_tab[(size_t)item_ids[b]*D_ + t];
}

// ---------------- logits + mask + new_targets (bf16 tables) ----------------
__global__ __launch_bounds__(256) void k_logits(
    const int* __restrict__ pos_t, const int* __restrict__ neg_t,
    const int* __restrict__ pos_l, const int* __restrict__ neg_l,
    const ushort* __restrict__ oeu, const ushort* __restrict__ oei,
    const float* __restrict__ user_out, const float* __restrict__ item_out,
    float* __restrict__ out)
{
  const int g = blockIdx.x*4 + (threadIdx.x >> 6);
  const int lane = threadIdx.x & 63;
  const int b = g / NT_;
  const int k = g - b*NT_;
  const int tid_ = (k < LP_) ? pos_t[b*LP_ + k] : neg_t[b*LNEG_ + (k-LP_)];
  const ushort* eu = oeu + (size_t)tid_*512;
  const ushort* ei = oei + (size_t)tid_*512;
  const float* uo = user_out + (size_t)b*512;
  const float* io = item_out + (size_t)b*512;
  const int d0 = lane*8;
  float s = 0.f;
  ushort4 a0 = *(const ushort4*)(eu+d0), a1 = *(const ushort4*)(eu+d0+4);
  float4 u0 = *(const float4*)(uo+d0), u1 = *(const float4*)(uo+d0+4);
  s += b2f(a0.x)*u0.x + b2f(a0.y)*u0.y + b2f(a0.z)*u0.z + b2f(a0.w)*u0.w;
  s += b2f(a1.x)*u1.x + b2f(a1.y)*u1.y + b2f(a1.z)*u1.z + b2f(a1.w)*u1.w;
  ushort4 c0 = *(const ushort4*)(ei+d0), c1 = *(const ushort4*)(ei+d0+4);
  float4 i0 = *(const float4*)(io+d0), i1 = *(const float4*)(io+d0+4);
  s += b2f(c0.x)*i0.x + b2f(c0.y)*i0.y + b2f(c0.z)*i0.z + b2f(c0.w)*i0.w;
  s += b2f(c1.x)*i1.x + b2f(c1.y)*i1.y + b2f(c1.z)*i1.z + b2f(c1.w)*i1.w;
  #pragma unroll
  for (int off=32; off>0; off>>=1) s += __shfl_xor(s, off, 64);
  if (lane == 0) {
    out[(size_t)b*NT_ + k] = s;
    float mv, nt;
    if (k < LP_) { mv = (k < pos_l[b]) ? 1.f : 0.f; nt = mv; }
    else         { mv = ((k - LP_) < neg_l[b]) ? 1.f : 0.f; nt = 0.f; }
    out[(size_t)B_*NT_   + (size_t)b*NT_ + k] = mv;
    out[(size_t)2*B_*NT_ + (size_t)b*NT_ + k] = nt;
  }
}

extern "C" void kernel_launch(void* const* d_in, const int* in_sizes, int n_in,
                              void* d_out, int out_size, void* d_ws, size_t ws_size,
                              hipStream_t stream)
{
  const int*   attr      = (const int*)d_in[0];
  const int*   attr_inds = (const int*)d_in[1];
  const float* attr_tf   = (const float*)d_in[2];
  const float* attr_feat = (const float*)d_in[3];
  const int*   attr_lens = (const int*)d_in[4];
  const int*   lens_u    = (const int*)d_in[5];
  const int*   lens_i    = (const int*)d_in[6];
  const int*   user_ids  = (const int*)d_in[7];
  const int*   item_ids  = (const int*)d_in[8];
  const int*   pos_t     = (const int*)d_in[9];
  const int*   pos_l     = (const int*)d_in[10];
  const int*   neg_t     = (const int*)d_in[11];
  const int*   neg_l     = (const int*)d_in[12];
  const float* attr_emb  = (const float*)d_in[13];
  const float* ind_emb   = (const float*)d_in[14];
  const float* user_tab  = (const float*)d_in[15];
  const float* item_tab  = (const float*)d_in[16];
  const float* oeu       = (const float*)d_in[17];
  const float* oei       = (const float*)d_in[18];
  const float* feat_w    = (const float*)d_in[19];
  const float* feat_b    = (const float*)d_in[20];
  const float* Wqkv      = (const float*)d_in[21];
  const float* bqkv      = (const float*)d_in[22];
  const float* Wo        = (const float*)d_in[23];
  const float* bo        = (const float*)d_in[24];
  const float* ln1s      = (const float*)d_in[25];
  const float* ln1b      = (const float*)d_in[26];
  const float* W1        = (const float*)d_in[27];
  const float* b1        = (const float*)d_in[28];
  const float* W2        = (const float*)d_in[29];
  const float* b2        = (const float*)d_in[30];
  const float* ln2s      = (const float*)d_in[31];
  const float* ln2b      = (const float*)d_in[32];

  // ---- ws layout: ints[768] | uo[B,512]f32 | io[B,512]f32 | xb[M,256]bf16 | weights bf16 | oeu_b | oei_b | chunk scratch ----
  int* ioff  = (int*)d_ws;            // off[513]
  int* ccnt  = ioff + 520;
  int* ccntp = ccnt + 64;
  float* ws = (float*)d_ws + 768;
  float* uo = ws;
  float* io = uo + (size_t)B_*512;
  ushort* xb   = (ushort*)(io + (size_t)B_*512);
  ushort* wq_b = xb + (size_t)M_*D_;
  ushort* wo_b = wq_b + (size_t)2*768*256;
  ushort* w1_b = wo_b + (size_t)2*256*256;
  ushort* w2_b = w1_b + (size_t)2*1024*256;
  ushort* oeu_b = w2_b + (size_t)2*256*1024;
  ushort* oei_b = oeu_b + (size_t)V_*512;
  float* scratch = (float*)(oei_b + (size_t)V_*512);

  const size_t fixed_floats = 768 + (size_t)B_*1024 + (size_t)M_*(D_/2) + 786432 + (size_t)V_*512;
  int Bc = 8;
  for (int cand = 512; cand >= 8; cand >>= 1) {
    size_t need = (fixed_floats + (size_t)cand*L_*512) * sizeof(float);
    if (need <= ws_size) { Bc = cand; break; }
  }
  const int nchunks = B_ / Bc;
  const size_t Mc = (size_t)Bc * L_;

  float* out = (float*)d_out;

  k_prefix<<<1, 512, 0, stream>>>(attr_lens, ioff, ccnt, ccntp, Bc, nchunks);
  k_f2b4<<<768, 256, 0, stream>>>(Wqkv, Wo, W1, W2, wq_b, wo_b, w1_b, w2_b);
  k_f2b<<<(V_*512)/2048, 256, 0, stream>>>(oeu, oeu_b);
  k_f2b<<<(V_*512)/2048, 256, 0, stream>>>(oei, oei_b);
  k_embed<<<M_*64/256, 256, 0, stream>>>(attr, attr_inds, attr_lens, ioff, attr_emb, ind_emb, xb);

  for (int l=0; l<NL_; ++l) {
    const float* bqkv_l = bqkv + (size_t)l*768;
    const float* bo_l   = bo   + (size_t)l*D_;
    const float* b1_l   = b1   + (size_t)l*FF_;
    const float* b2_l   = b2   + (size_t)l*D_;
    for (int c=0; c<nchunks; ++c) {
      const int* offc = ioff + c*Bc;
      const int* cntp = ccntp + c;
      const int* cnt  = ccnt + c;
      ushort* qkv_b = (ushort*)scratch;                 // [Mc,768] bf16
      ushort* ctx_b = (ushort*)(scratch + Mc*384);      // [Mc,256] bf16

      k_gemm_mfma<1,0><<<dim3(768/128, Mc/128), 256, 0, stream>>>(
          xb, offc, cntp, wq_b + (size_t)l*768*256, bqkv_l, qkv_b, 768, 256);
      k_attn_mfma<<<Bc*H_, 256, 0, stream>>>(qkv_b, ctx_b, offc);
      k_gemm_ln<<<Mc/128, 512, 0, stream>>>(
          ctx_b, cntp, cnt, offc, wo_b + (size_t)l*256*256, bo_l,
          ln1s + (size_t)l*D_, ln1b + (size_t)l*D_, xb, 256);
      k_ffn<<<Mc/64, 512, 0, stream>>>(
          cntp, cnt, offc, w1_b + (size_t)l*1024*256, b1_l,
          w2_b + (size_t)l*256*1024, b2_l,
          ln2s + (size_t)l*D_, ln2b + (size_t)l*D_, xb);
    }
  }
  k_pool<<<B_, 256, 0, stream>>>(xb, ioff, attr_tf, attr_feat, lens_u, lens_i, user_ids, item_ids,
                                 user_tab, item_tab, feat_w, feat_b, uo, io);
  k_logits<<<B_*NT_/4, 256, 0, stream>>>(pos_t, neg_t, pos_l, neg_l, oeu_b, oei_b, uo, io, out);
}

// Round 15
// 628.548 us; speedup vs baseline: 1.0529x; 1.0529x over previous
//
#include <hip/hip_runtime.h>
#include <hip/hip_bf16.h>
#include <cstdint>
#include <cstddef>

#define B_ 512
#define L_ 192
#define D_ 256
#define H_ 4
#define DH_ 64
#define FF_ 1024
#define NL_ 2
#define LP_ 30
#define LNEG_ 300
#define NF_ 13
#define M_ (B_*L_)   // 98304 tokens
#define NT_ 330      // LP_+LNEG_
#define V_ 30000

typedef __attribute__((ext_vector_type(8))) short bf16x8;
typedef __attribute__((ext_vector_type(4))) float f32x4;

// RNE float -> bf16 bits (finite inputs only)
__device__ __forceinline__ ushort f2b(float f) {
  union { float f; uint32_t u; } v; v.f = f;
  uint32_t u = v.u;
  return (ushort)((u + 0x7FFFu + ((u >> 16) & 1u)) >> 16);
}
__device__ __forceinline__ float b2f(ushort u) {
  union { uint32_t u; float f; } v; v.u = (uint32_t)u << 16; return v.f;
}
__device__ __forceinline__ void stage16(const ushort* src, char* dst) {
  __builtin_amdgcn_global_load_lds((const __attribute__((address_space(1))) unsigned int*)src,
                                   (__attribute__((address_space(3))) unsigned int*)dst, 16, 0, 0);
}

// ---------------- prefix sums of lens: off[513], per-chunk counts ----------------
__global__ __launch_bounds__(512) void k_prefix(
    const int* __restrict__ lens, int* __restrict__ off,
    int* __restrict__ ccnt, int* __restrict__ ccntp, int Bc, int nchunks)
{
  const int t = threadIdx.x;
  int s = 0;
  for (int i = 0; i < t; ++i) s += lens[i];
  off[t] = s;
  if (t == 511) off[512] = s + lens[511];
  if (t < nchunks) {
    int s2 = 0;
    const int c0 = t * Bc;
    for (int i = 0; i < Bc; ++i) s2 += lens[c0 + i];
    ccnt[t]  = s2;
    ccntp[t] = (s2 + 127) & ~127;
  }
}

// ---------------- generic fp32 -> bf16 conversion (2048 elems/block) ----------------
__global__ __launch_bounds__(256) void k_f2b(const float* __restrict__ in, ushort* __restrict__ out) {
  const int i = (blockIdx.x*256 + threadIdx.x)*8;
  float4 a = *(const float4*)(in+i);
  float4 b = *(const float4*)(in+i+4);
  ushort4 o1; o1.x=f2b(a.x); o1.y=f2b(a.y); o1.z=f2b(a.z); o1.w=f2b(a.w);
  ushort4 o2; o2.x=f2b(b.x); o2.y=f2b(b.y); o2.z=f2b(b.z); o2.w=f2b(b.w);
  *(ushort4*)(out+i)   = o1;
  *(ushort4*)(out+i+4) = o2;
}

// ---------------- weight conversion, all 4 groups in one launch ----------------
__global__ __launch_bounds__(256) void k_f2b4(
    const float* __restrict__ wq, const float* __restrict__ wo,
    const float* __restrict__ w1, const float* __restrict__ w2,
    ushort* __restrict__ oq, ushort* __restrict__ oo,
    ushort* __restrict__ o1, ushort* __restrict__ o2)
{
  int bb = blockIdx.x;
  const float* in; ushort* out; int base;
  if (bb < 192)      { in = wq; out = oq; base = bb; }
  else if (bb < 256) { in = wo; out = oo; base = bb - 192; }
  else if (bb < 512) { in = w1; out = o1; base = bb - 256; }
  else               { in = w2; out = o2; base = bb - 512; }
  const int i = base*2048 + threadIdx.x*8;
  float4 a = *(const float4*)(in+i);
  float4 b = *(const float4*)(in+i+4);
  ushort4 q1; q1.x=f2b(a.x); q1.y=f2b(a.y); q1.z=f2b(a.z); q1.w=f2b(a.w);
  ushort4 q2; q2.x=f2b(b.x); q2.y=f2b(b.y); q2.z=f2b(b.z); q2.w=f2b(b.w);
  *(ushort4*)(out+i)   = q1;
  *(ushort4*)(out+i+4) = q2;
}

// ---------------- embedding gather into COMPACT token space (bf16 state only) ----------------
__global__ __launch_bounds__(256) void k_embed(
    const int* __restrict__ attr, const int* __restrict__ inds,
    const int* __restrict__ lens, const int* __restrict__ off,
    const float* __restrict__ attr_emb, const float* __restrict__ ind_emb,
    ushort* __restrict__ xb)
{
  int idx = blockIdx.x*256 + threadIdx.x;
  int token = idx >> 6;
  int c = (idx & 63) * 4;
  int b = token / L_;
  int l = token - b*L_;
  if (l >= lens[b]) return;
  size_t crow = (size_t)off[b] + l;
  int a = attr[token];
  int id = inds[token];
  const float4 e  = *(const float4*)(attr_emb + (size_t)a*D_ + c);
  const float4 ie = *(const float4*)(ind_emb  + (size_t)id*D_ + c);
  ushort4 ob; ob.x=f2b(e.x+ie.x); ob.y=f2b(e.y+ie.y); ob.z=f2b(e.z+ie.z); ob.w=f2b(e.w+ie.w);
  *(ushort4*)(xb + crow*D_ + c) = ob;
}

// ---------------- bf16 MFMA GEMM (128x128), swizzled LDS, SWAPPED operands ----------------
template<int OUT_BF16, int RELU>
__global__ __launch_bounds__(256) void k_gemm_mfma(
    const ushort* __restrict__ A, const int* __restrict__ aoffp,
    const int* __restrict__ cntp,
    const ushort* __restrict__ W, const float* __restrict__ bias,
    void* __restrict__ Cv, int N, int K)
{
  if ((int)blockIdx.y * 128 >= *cntp) return;
  __shared__ alignas(16) ushort As[8192];
  __shared__ alignas(16) ushort Bs[8192];
  const int abase = *aoffp;
  const int tid = threadIdx.x;
  const int w = tid >> 6, l = tid & 63;
  const int g = l >> 4, c16 = l & 15;
  const int m0 = blockIdx.y*128, n0 = blockIdx.x*128;
  const int wr = w >> 1, wc = w & 1;
  const int swzr = (c16 & 7) << 4;

  f32x4 acc[4][4];
  #pragma unroll
  for (int i=0;i<4;++i)
    #pragma unroll
    for (int j=0;j<4;++j) acc[i][j] = (f32x4){0.f,0.f,0.f,0.f};

  for (int k0=0; k0<K; k0+=64) {
    #pragma unroll
    for (int i=0;i<4;++i) {
      const int li  = i*4096 + tid*16;
      const int row = li >> 7;
      const int col = ((li & 127) ^ ((row & 7) << 4)) >> 1;
      stage16(A + (size_t)(abase+m0+row)*K + k0 + col, (char*)(As) + i*4096 + w*1024);
      stage16(W + (size_t)(n0+row)*K + k0 + col,       (char*)(Bs) + i*4096 + w*1024);
    }
    __syncthreads();
    #pragma unroll
    for (int ks=0; ks<2; ++ks) {
      const int cb = ((g*16 + ks*64) ^ swzr) >> 1;
      bf16x8 af[4], bfr[4];
      #pragma unroll
      for (int i2=0;i2<4;++i2) {
        af[i2]  = *(const bf16x8*)(As + (size_t)(wr*64 + i2*16 + c16)*64 + cb);
        bfr[i2] = *(const bf16x8*)(Bs + (size_t)(wc*64 + i2*16 + c16)*64 + cb);
      }
      #pragma unroll
      for (int mi=0;mi<4;++mi)
        #pragma unroll
        for (int ni=0;ni<4;++ni)
          acc[mi][ni] = __builtin_amdgcn_mfma_f32_16x16x32_bf16(bfr[ni], af[mi], acc[mi][ni], 0,0,0);
    }
    __syncthreads();
  }
  #pragma unroll
  for (int ni=0;ni<4;++ni) {
    const int nc = n0 + wc*64 + ni*16 + 4*g;
    const float4 bv = *(const float4*)(bias + nc);
    #pragma unroll
    for (int mi=0;mi<4;++mi) {
      float v0 = acc[mi][ni][0] + bv.x;
      float v1 = acc[mi][ni][1] + bv.y;
      float v2 = acc[mi][ni][2] + bv.z;
      float v3 = acc[mi][ni][3] + bv.w;
      if (RELU) { v0=fmaxf(v0,0.f); v1=fmaxf(v1,0.f); v2=fmaxf(v2,0.f); v3=fmaxf(v3,0.f); }
      const size_t idx = (size_t)(m0 + wr*64 + mi*16 + c16)*N + nc;
      if (OUT_BF16) {
        ushort4 o; o.x=f2b(v0); o.y=f2b(v1); o.z=f2b(v2); o.w=f2b(v3);
        *(ushort4*)((ushort*)Cv + idx) = o;
      } else {
        float4 o; o.x=v0; o.y=v1; o.z=v2; o.w=v3;
        *(float4*)((float*)Cv + idx) = o;
      }
    }
  }
}

// ---------------- fused GEMM(N=256) + residual + LN, bf16 state, swizzled, SWAPPED ----------------
__global__ __launch_bounds__(512) void k_gemm_ln(
    const ushort* __restrict__ A,
    const int* __restrict__ cntp, const int* __restrict__ cnt,
    const int* __restrict__ xoffp,
    const ushort* __restrict__ W,
    const float* __restrict__ bias,
    const float* __restrict__ lns, const float* __restrict__ lnb,
    ushort* __restrict__ xb, int K)
{
  const int m0 = blockIdx.x*128;
  if (m0 >= *cntp) return;
  __shared__ alignas(16) ushort As[8192];
  __shared__ alignas(16) ushort Bs[16384];
  __shared__ float red[4][2][128];
  const int tid = threadIdx.x;
  const int w = tid >> 6, l = tid & 63;
  const int g = l >> 4, c16 = l & 15;
  const int wr = w >> 2, wc = w & 3;
  const int swzr = (c16 & 7) << 4;

  f32x4 acc[4][4];
  #pragma unroll
  for (int i=0;i<4;++i)
    #pragma unroll
    for (int j=0;j<4;++j) acc[i][j] = (f32x4){0.f,0.f,0.f,0.f};

  for (int k0=0; k0<K; k0+=64) {
    #pragma unroll
    for (int i=0;i<2;++i) {
      const int li  = i*8192 + tid*16;
      const int row = li >> 7;
      const int col = ((li & 127) ^ ((row & 7) << 4)) >> 1;
      stage16(A + (size_t)(m0+row)*K + k0 + col, (char*)(As) + i*8192 + w*1024);
    }
    #pragma unroll
    for (int i=0;i<4;++i) {
      const int li  = i*8192 + tid*16;
      const int row = li >> 7;
      const int col = ((li & 127) ^ ((row & 7) << 4)) >> 1;
      stage16(W + (size_t)row*K + k0 + col, (char*)(Bs) + i*8192 + w*1024);
    }
    __syncthreads();
    #pragma unroll
    for (int ks=0; ks<2; ++ks) {
      const int cb = ((g*16 + ks*64) ^ swzr) >> 1;
      bf16x8 af[4], bfr[4];
      #pragma unroll
      for (int i2=0;i2<4;++i2) {
        af[i2]  = *(const bf16x8*)(As + (size_t)(wr*64 + i2*16 + c16)*64 + cb);
        bfr[i2] = *(const bf16x8*)(Bs + (size_t)(wc*64 + i2*16 + c16)*64 + cb);
      }
      #pragma unroll
      for (int mi=0;mi<4;++mi)
        #pragma unroll
        for (int ni=0;ni<4;++ni)
          acc[mi][ni] = __builtin_amdgcn_mfma_f32_16x16x32_bf16(bfr[ni], af[mi], acc[mi][ni], 0,0,0);
    }
    __syncthreads();
  }

  const int xbase = *xoffp + m0;
  float4 bv[4], sv[4], bb[4];
  #pragma unroll
  for (int ni=0;ni<4;++ni) {
    const int nc = wc*64 + ni*16 + 4*g;
    bv[ni] = *(const float4*)(bias + nc);
    sv[ni] = *(const float4*)(lns + nc);
    bb[ni] = *(const float4*)(lnb + nc);
  }
  float ps[4], pq[4];
  #pragma unroll
  for (int mi=0;mi<4;++mi) {
    ps[mi]=0.f; pq[mi]=0.f;
    const int lrow = wr*64 + mi*16 + c16;
    const ushort* xr = xb + (size_t)(xbase + lrow)*256;
    #pragma unroll
    for (int ni=0;ni<4;++ni) {
      const int nc = wc*64 + ni*16 + 4*g;
      ushort4 rx = *(const ushort4*)(xr + nc);
      float y0 = acc[mi][ni][0] + bv[ni].x + b2f(rx.x);
      float y1 = acc[mi][ni][1] + bv[ni].y + b2f(rx.y);
      float y2 = acc[mi][ni][2] + bv[ni].z + b2f(rx.z);
      float y3 = acc[mi][ni][3] + bv[ni].w + b2f(rx.w);
      acc[mi][ni][0]=y0; acc[mi][ni][1]=y1; acc[mi][ni][2]=y2; acc[mi][ni][3]=y3;
      ps[mi] += (y0+y1)+(y2+y3);
      pq[mi] += (y0*y0+y1*y1)+(y2*y2+y3*y3);
    }
  }
  #pragma unroll
  for (int mi=0;mi<4;++mi) {
    ps[mi] += __shfl_xor(ps[mi], 16, 64);
    pq[mi] += __shfl_xor(pq[mi], 16, 64);
    ps[mi] += __shfl_xor(ps[mi], 32, 64);
    pq[mi] += __shfl_xor(pq[mi], 32, 64);
  }
  if (g == 0) {
    #pragma unroll
    for (int mi=0;mi<4;++mi) {
      const int lrow = wr*64 + mi*16 + c16;
      red[wc][0][lrow] = ps[mi];
      red[wc][1][lrow] = pq[mi];
    }
  }
  __syncthreads();
  const int cexact = *cnt;
  #pragma unroll
  for (int mi=0;mi<4;++mi) {
    const int lrow = wr*64 + mi*16 + c16;
    float tsum = red[0][0][lrow] + red[1][0][lrow] + red[2][0][lrow] + red[3][0][lrow];
    float tsq  = red[0][1][lrow] + red[1][1][lrow] + red[2][1][lrow] + red[3][1][lrow];
    float mean = tsum * (1.f/256.f);
    float var  = tsq * (1.f/256.f) - mean*mean;
    float inv  = rsqrtf(var + 1e-5f);
    if (m0 + lrow < cexact) {
      ushort* xbr = xb + (size_t)(xbase + lrow)*256;
      #pragma unroll
      for (int ni=0;ni<4;++ni) {
        const int nc = wc*64 + ni*16 + 4*g;
        ushort4 o;
        o.x = f2b((acc[mi][ni][0]-mean)*inv*sv[ni].x + bb[ni].x);
        o.y = f2b((acc[mi][ni][1]-mean)*inv*sv[ni].y + bb[ni].y);
        o.z = f2b((acc[mi][ni][2]-mean)*inv*sv[ni].z + bb[ni].z);
        o.w = f2b((acc[mi][ni][3]-mean)*inv*sv[ni].w + bb[ni].w);
        *(ushort4*)(xbr + nc) = o;
      }
    }
  }
}

// ---------------- fused FFN v4+setprio: 64 tokens/block, 80KB LDS -> 2 blocks/CU ----------------
// (round-12 structure; s_setprio(1/0) wraps each step's MFMA cluster — T5)
__global__ __launch_bounds__(512) void k_ffn(
    const int* __restrict__ cntp, const int* __restrict__ cnt,
    const int* __restrict__ xoffp,
    const ushort* __restrict__ W1, const float* __restrict__ b1,
    const ushort* __restrict__ W2, const float* __restrict__ b2,
    const float* __restrict__ lns, const float* __restrict__ lnb,
    ushort* __restrict__ xb)
{
  const int m0 = blockIdx.x*64;
  if (m0 >= *cntp) return;
  __shared__ alignas(16) char lds[81920];
  char* Xs = lds;                 // [0, 32768)
  char* Wb = lds + 32768;         // [32768, 65536): 2 x 16KB
  char* Hs = lds + 65536;         // [65536, 81920)
  float* red = (float*)(lds + 32768);   // reuses Wb region after main loop
  const int tid = threadIdx.x;
  const int w = tid >> 6, l = tid & 63;
  const int g = l >> 4, c16 = l & 15;
  const int wr = w >> 2, wc = w & 3;
  const int swzr = (c16 & 7) << 4;
  const int xbase = *xoffp + m0;

  int tokl[2];
  #pragma unroll
  for (int mi=0;mi<2;++mi) tokl[mi] = wr*32 + mi*16 + c16;

  // ---- prologue: stage X once (32KB) + W1(s=0,kc=0) chunk ----
  #pragma unroll
  for (int i=0;i<4;++i) {
    const int li = i*8192 + tid*16;
    const int row = li >> 9;                       // 512B per token row
    const int colb = (li & 511) ^ ((row & 7) << 4);
    stage16(xb + (size_t)(xbase+row)*256 + (colb>>1), Xs + i*8192 + w*1024);
  }
  #pragma unroll
  for (int i=0;i<2;++i) {
    const int li = i*8192 + tid*16;
    const int row = li >> 7;
    const int colb = (li & 127) ^ ((row & 7) << 4);
    stage16(W1 + (size_t)row*256 + (colb>>1), Wb + i*8192 + w*1024);
  }
  __syncthreads();

  f32x4 tac[2][4];
  #pragma unroll
  for (int i=0;i<2;++i)
    #pragma unroll
    for (int j=0;j<4;++j) tac[i][j] = (f32x4){0.f,0.f,0.f,0.f};

  int pp = 0;
  for (int s=0; s<8; ++s) {
    f32x4 hac[2][2];
    #pragma unroll
    for (int i=0;i<2;++i)
      #pragma unroll
      for (int j=0;j<2;++j) hac[i][j] = (f32x4){0.f,0.f,0.f,0.f};

    // ---- W1 steps kc=0..3: h += W1_chunk @ X ----
    #pragma unroll
    for (int kc=0; kc<4; ++kc) {
      char* cur = Wb + pp*16384;
      char* nxt = Wb + (pp^1)*16384;
      if (kc < 3) {                 // prefetch next W1 chunk
        #pragma unroll
        for (int i=0;i<2;++i) {
          const int li = i*8192 + tid*16;
          const int row = li >> 7;
          const int colb = (li & 127) ^ ((row & 7) << 4);
          stage16(W1 + (size_t)(s*128+row)*256 + (kc+1)*64 + (colb>>1), nxt + i*8192 + w*1024);
        }
      } else {                      // prefetch W2 chunk (dh=0,kc2=0)
        #pragma unroll
        for (int i=0;i<2;++i) {
          const int li = i*8192 + tid*16;
          const int row = li >> 7;
          const int colb = (li & 127) ^ ((row & 7) << 4);
          stage16(W2 + (size_t)row*1024 + s*128 + (colb>>1), nxt + i*8192 + w*1024);
        }
      }
      __builtin_amdgcn_s_setprio(1);
      #pragma unroll
      for (int ks=0; ks<2; ++ks) {
        const int cbw = (ks*64 + g*16) ^ swzr;
        bf16x8 w1f[2], xf[2];
        #pragma unroll
        for (int ni=0;ni<2;++ni)
          w1f[ni] = *(const bf16x8*)(cur + (wc*32 + ni*16 + c16)*128 + cbw);
        #pragma unroll
        for (int mi=0;mi<2;++mi)
          xf[mi] = *(const bf16x8*)(Xs + tokl[mi]*512 + ((kc*128 + ks*64 + g*16) ^ swzr));
        #pragma unroll
        for (int mi=0;mi<2;++mi)
          #pragma unroll
          for (int ni=0;ni<2;++ni)
            hac[mi][ni] = __builtin_amdgcn_mfma_f32_16x16x32_bf16(w1f[ni], xf[mi], hac[mi][ni], 0,0,0);
      }
      __builtin_amdgcn_s_setprio(0);
      if (kc == 3) {               // bias+relu -> Hs (ushort4, swizzled by token row)
        #pragma unroll
        for (int ni=0;ni<2;++ni) {
          const int ffc = wc*32 + ni*16 + 4*g;
          const float4 bb1 = *(const float4*)(b1 + s*128 + ffc);
          #pragma unroll
          for (int mi=0;mi<2;++mi) {
            ushort4 o;
            o.x = f2b(fmaxf(hac[mi][ni][0] + bb1.x, 0.f));
            o.y = f2b(fmaxf(hac[mi][ni][1] + bb1.y, 0.f));
            o.z = f2b(fmaxf(hac[mi][ni][2] + bb1.z, 0.f));
            o.w = f2b(fmaxf(hac[mi][ni][3] + bb1.w, 0.f));
            *(ushort4*)(Hs + tokl[mi]*256 + ((ffc*2) ^ swzr)) = o;
          }
        }
      }
      __syncthreads();
      pp ^= 1;
    }

    // ---- W2 steps t2=0..3 (dh=t2>>1, kc2=t2&1): t[dh] += W2_chunk @ h ----
    #pragma unroll
    for (int t2=0; t2<4; ++t2) {
      const int dh = t2 >> 1, kc2 = t2 & 1;
      char* cur = Wb + pp*16384;
      char* nxt = Wb + (pp^1)*16384;
      if (t2 < 3) {                 // prefetch next W2 chunk
        const int nd = (t2+1) >> 1, nk = (t2+1) & 1;
        #pragma unroll
        for (int i=0;i<2;++i) {
          const int li = i*8192 + tid*16;
          const int row = li >> 7;
          const int colb = (li & 127) ^ ((row & 7) << 4);
          stage16(W2 + (size_t)(nd*128+row)*1024 + s*128 + nk*64 + (colb>>1), nxt + i*8192 + w*1024);
        }
      } else if (s < 7) {           // prefetch next slice's W1 chunk 0
        #pragma unroll
        for (int i=0;i<2;++i) {
          const int li = i*8192 + tid*16;
          const int row = li >> 7;
          const int colb = (li & 127) ^ ((row & 7) << 4);
          stage16(W1 + (size_t)((s+1)*128+row)*256 + (colb>>1), nxt + i*8192 + w*1024);
        }
      }
      __builtin_amdgcn_s_setprio(1);
      #pragma unroll
      for (int ks=0; ks<2; ++ks) {
        const int cbw = (ks*64 + g*16) ^ swzr;
        bf16x8 w2f[2], hf[2];
        #pragma unroll
        for (int ni=0;ni<2;++ni)
          w2f[ni] = *(const bf16x8*)(cur + (wc*32 + ni*16 + c16)*128 + cbw);
        #pragma unroll
        for (int mi=0;mi<2;++mi)
          hf[mi] = *(const bf16x8*)(Hs + tokl[mi]*256 + ((kc2*128 + ks*64 + g*16) ^ swzr));
        #pragma unroll
        for (int mi=0;mi<2;++mi)
          #pragma unroll
          for (int ni=0;ni<2;++ni)
            tac[mi][dh*2+ni] = __builtin_amdgcn_mfma_f32_16x16x32_bf16(w2f[ni], hf[mi], tac[mi][dh*2+ni], 0,0,0);
      }
      __builtin_amdgcn_s_setprio(0);
      __syncthreads();
      pp ^= 1;
    }
  }

  // ---- epilogue: y = t + b2 + resid; LN over 256; write xb. col(n) = (n>>1)*128 + wc*32 + (n&1)*16 + 4g ----
  float4 bv[4], sv[4], bb[4];
  #pragma unroll
  for (int n=0;n<4;++n) {
    const int nc = (n>>1)*128 + wc*32 + (n&1)*16 + 4*g;
    bv[n] = *(const float4*)(b2 + nc);
    sv[n] = *(const float4*)(lns + nc);
    bb[n] = *(const float4*)(lnb + nc);
  }
  float ps[2], pq[2];
  #pragma unroll
  for (int mi=0;mi<2;++mi) {
    ps[mi]=0.f; pq[mi]=0.f;
    const ushort* xr = xb + (size_t)(xbase + tokl[mi])*256;
    #pragma unroll
    for (int n=0;n<4;++n) {
      const int nc = (n>>1)*128 + wc*32 + (n&1)*16 + 4*g;
      ushort4 rx = *(const ushort4*)(xr + nc);
      float y0 = tac[mi][n][0] + bv[n].x + b2f(rx.x);
      float y1 = tac[mi][n][1] + bv[n].y + b2f(rx.y);
      float y2 = tac[mi][n][2] + bv[n].z + b2f(rx.z);
      float y3 = tac[mi][n][3] + bv[n].w + b2f(rx.w);
      tac[mi][n][0]=y0; tac[mi][n][1]=y1; tac[mi][n][2]=y2; tac[mi][n][3]=y3;
      ps[mi] += (y0+y1)+(y2+y3);
      pq[mi] += (y0*y0+y1*y1)+(y2*y2+y3*y3);
    }
  }
  #pragma unroll
  for (int mi=0;mi<2;++mi) {
    ps[mi] += __shfl_xor(ps[mi], 16, 64);
    pq[mi] += __shfl_xor(pq[mi], 16, 64);
    ps[mi] += __shfl_xor(ps[mi], 32, 64);
    pq[mi] += __shfl_xor(pq[mi], 32, 64);
  }
  if (g == 0) {
    #pragma unroll
    for (int mi=0;mi<2;++mi) {
      red[(wc*2+0)*64 + tokl[mi]] = ps[mi];
      red[(wc*2+1)*64 + tokl[mi]] = pq[mi];
    }
  }
  __syncthreads();
  const int cexact = *cnt;
  #pragma unroll
  for (int mi=0;mi<2;++mi) {
    const int lrow = tokl[mi];
    float tsum = red[0*64+lrow] + red[2*64+lrow] + red[4*64+lrow] + red[6*64+lrow];
    float tsq  = red[1*64+lrow] + red[3*64+lrow] + red[5*64+lrow] + red[7*64+lrow];
    float mean = tsum * (1.f/256.f);
    float var  = tsq * (1.f/256.f) - mean*mean;
    float inv  = rsqrtf(var + 1e-5f);
    if (m0 + lrow < cexact) {
      ushort* xbr = xb + (size_t)(xbase + lrow)*256;
      #pragma unroll
      for (int n=0;n<4;++n) {
        const int nc = (n>>1)*128 + wc*32 + (n&1)*16 + 4*g;
        ushort4 o;
        o.x = f2b((tac[mi][n][0]-mean)*inv*sv[n].x + bb[n].x);
        o.y = f2b((tac[mi][n][1]-mean)*inv*sv[n].y + bb[n].y);
        o.z = f2b((tac[mi][n][2]-mean)*inv*sv[n].z + bb[n].z);
        o.w = f2b((tac[mi][n][3]-mean)*inv*sv[n].w + bb[n].w);
        *(ushort4*)(xbr + nc) = o;
      }
    }
  }
}

// ---------------- MFMA flash attention on compact rows: block per (b,h) ----------------
__global__ __launch_bounds__(256) void k_attn_mfma(
    const ushort* __restrict__ qkv, ushort* __restrict__ ctx,
    const int* __restrict__ offc)
{
  __shared__ alignas(16) char lds[81920];
  char* Kb = lds;
  char* Vt = lds + 24576;
  const int tid = threadIdx.x;
  const int w = tid >> 6, l = tid & 63;
  const int g = l >> 4, c = l & 15;
  char* Pw = lds + 57344 + w*6144;
  const int bl = blockIdx.x >> 2, h = blockIdx.x & 3;
  const int rowbase = offc[bl] - offc[0];
  const int len = offc[bl+1] - offc[bl];
  const int nkt = (len + 15) >> 4;
  const int nkf = (len + 31) >> 5;
  const ushort* base = qkv + (size_t)rowbase*768;
  ushort* cbase = ctx + (size_t)rowbase*256;

  const int lenk8 = nkt*16*8;
  for (int idx = tid; idx < lenk8; idx += 256) {
    int row = idx >> 3, ch = idx & 7;
    uint4 v = *(const uint4*)(base + (size_t)row*768 + 256 + h*64 + ch*8);
    *(uint4*)(Kb + ((row*128 + ch*16) ^ ((row&7)<<4))) = v;
  }
  {
    const int lenv = nkf*32;
    int d0 = (tid & 15)*4;
    for (int key = tid >> 4; key < lenv; key += 16) {
      ushort4 v = *(const ushort4*)(base + (size_t)key*768 + 512 + h*64 + d0);
      ushort vv[4] = {v.x, v.y, v.z, v.w};
      #pragma unroll
      for (int j=0;j<4;++j) {
        int d = d0 + j;
        *(ushort*)(Vt + ((d*512 + key*2) ^ ((d&7)<<4))) = vv[j];
      }
    }
  }
  __syncthreads();

  for (int t = nkt; t < 2*nkf; ++t) {
    #pragma unroll
    for (int r=0;r<4;++r) {
      int q = 4*g + r;
      *(ushort*)(Pw + (((t>>1)*1024 + q*64 + ((t&1)*16 + c)*2) ^ (((q>>2)&3)<<4))) = 0;
    }
  }

  const int nst = (len + 15) >> 4;
  for (int s = w; s < nst; s += 4) {
    const ushort* qp = base + (size_t)(s*16 + c)*768 + h*64 + g*8;
    bf16x8 aq0 = *(const bf16x8*)qp;
    bf16x8 aq1 = *(const bf16x8*)(qp + 32);

    f32x4 sc[12];
    #pragma unroll
    for (int t=0;t<12;++t) {
      sc[t] = (f32x4){0.f,0.f,0.f,0.f};
      if (t < nkt) {
        int ba0 = ((t*16 + c)*128 + g*16)      ^ ((c&7)<<4);
        int ba1 = ((t*16 + c)*128 + g*16 + 64) ^ ((c&7)<<4);
        bf16x8 k0 = *(const bf16x8*)(Kb + ba0);
        bf16x8 k1 = *(const bf16x8*)(Kb + ba1);
        sc[t] = __builtin_amdgcn_mfma_f32_16x16x32_bf16(aq0, k0, sc[t], 0,0,0);
        sc[t] = __builtin_amdgcn_mfma_f32_16x16x32_bf16(aq1, k1, sc[t], 0,0,0);
        if (t == nkt-1 && t*16 + c >= len)
          sc[t] = (f32x4){-1e30f,-1e30f,-1e30f,-1e30f};
      }
    }
    float mr[4] = {-1e30f,-1e30f,-1e30f,-1e30f};
    #pragma unroll
    for (int t=0;t<12;++t) if (t<nkt) {
      #pragma unroll
      for (int r=0;r<4;++r) mr[r] = fmaxf(mr[r], sc[t][r]);
    }
    #pragma unroll
    for (int r=0;r<4;++r) {
      mr[r] = fmaxf(mr[r], __shfl_xor(mr[r], 1, 16));
      mr[r] = fmaxf(mr[r], __shfl_xor(mr[r], 2, 16));
      mr[r] = fmaxf(mr[r], __shfl_xor(mr[r], 4, 16));
      mr[r] = fmaxf(mr[r], __shfl_xor(mr[r], 8, 16));
    }
    float sr[4] = {0.f,0.f,0.f,0.f};
    #pragma unroll
    for (int t=0;t<12;++t) if (t<nkt) {
      #pragma unroll
      for (int r=0;r<4;++r) {
        float p = __expf((sc[t][r] - mr[r]) * 0.125f);
        sr[r] += p;
        int q = 4*g + r;
        *(ushort*)(Pw + (((t>>1)*1024 + q*64 + ((t&1)*16 + c)*2) ^ (((q>>2)&3)<<4))) = f2b(p);
      }
    }
    #pragma unroll
    for (int r=0;r<4;++r) {
      sr[r] += __shfl_xor(sr[r], 1, 16);
      sr[r] += __shfl_xor(sr[r], 2, 16);
      sr[r] += __shfl_xor(sr[r], 4, 16);
      sr[r] += __shfl_xor(sr[r], 8, 16);
    }
    f32x4 oa[4];
    #pragma unroll
    for (int dt=0;dt<4;++dt) oa[dt] = (f32x4){0.f,0.f,0.f,0.f};
    #pragma unroll
    for (int kf=0;kf<6;++kf) if (kf<nkf) {
      bf16x8 pf = *(const bf16x8*)(Pw + ((kf*1024 + c*64 + g*16) ^ (((c>>2)&3)<<4)));
      #pragma unroll
      for (int dt=0;dt<4;++dt) {
        int d = dt*16 + c;
        bf16x8 vf = *(const bf16x8*)(Vt + ((d*512 + kf*64 + g*16) ^ ((d&7)<<4)));
        oa[dt] = __builtin_amdgcn_mfma_f32_16x16x32_bf16(pf, vf, oa[dt], 0,0,0);
      }
    }
    float inv[4];
    #pragma unroll
    for (int r=0;r<4;++r) inv[r] = 1.f / sr[r];
    ushort* orow = cbase + (size_t)(s*16)*256 + h*64;
    #pragma unroll
    for (int r=0;r<4;++r) {
      int q = 4*g + r;
      if (s*16 + q < len) {
        #pragma unroll
        for (int dt=0;dt<4;++dt)
          orow[(size_t)q*256 + dt*16 + c] = f2b(oa[dt][r] * inv[r]);
      }
    }
  }
}

// ---------------- ragged weighted pooling (compact bf16 x) + concat id embeddings ----------------
__global__ __launch_bounds__(256) void k_pool(
    const ushort* __restrict__ xb, const int* __restrict__ off,
    const float* __restrict__ attr_tf, const float* __restrict__ attr_feat,
    const int* __restrict__ lens_u, const int* __restrict__ lens_i,
    const int* __restrict__ user_ids, const int* __restrict__ item_ids,
    const float* __restrict__ user_tab, const float* __restrict__ item_tab,
    const float* __restrict__ feat_w, const float* __restrict__ feat_b,
    float* __restrict__ user_out, float* __restrict__ item_out)
{
  __shared__ float wu[L_], tf[L_];
  const int b = blockIdx.x;
  const int t = threadIdx.x;
  if (t < L_) {
    const float* f = attr_feat + ((size_t)b*L_ + t)*NF_;
    float sacc = feat_b[0];
    #pragma unroll
    for (int j=0;j<NF_;++j) sacc = fmaf(f[j], feat_w[j], sacc);
    wu[t] = 1.f/(1.f+__expf(-sacc));
    tf[t] = attr_tf[b*L_+t];
  }
  __syncthreads();
  const int Lu = lens_u[b], Li = lens_i[b];
  const ushort* xrow = xb + (size_t)off[b]*D_;
  float su=0.f, si=0.f;
  for (int l=0;l<Lu+Li;++l) {
    float val = b2f(xrow[(size_t)l*D_ + t]) * tf[l];
    if (l < Lu) su = fmaf(val, wu[l], su);
    else        si = fmaf(val, 1.f-wu[l], si);
  }
  user_out[(size_t)b*512 + t]       = su/(float)Lu;
  item_out[(size_t)b*512 + t]       = si/(float)Li;
  user_out[(size_t)b*512 + 256 + t] = user_tab[(size_t)user_ids[b]*D_ + t];
  item_out[(size_t)b*512 + 256 + t] = item_tab[(size_t)item_ids[b]*D_ + t];
}

// ---------------- logits + mask + new_targets (bf16 tables) ----------------
__global__ __launch_bounds__(256) void k_logits(
    const int* __restrict__ pos_t, const int* __restrict__ neg_t,
    const int* __restrict__ pos_l, const int* __restrict__ neg_l,
    const ushort* __restrict__ oeu, const ushort* __restrict__ oei,
    const float* __restrict__ user_out, const float* __restrict__ item_out,
    float* __restrict__ out)
{
  const int g = blockIdx.x*4 + (threadIdx.x >> 6);
  const int lane = threadIdx.x & 63;
  const int b = g / NT_;
  const int k = g - b*NT_;
  const int tid_ = (k < LP_) ? pos_t[b*LP_ + k] : neg_t[b*LNEG_ + (k-LP_)];
  const ushort* eu = oeu + (size_t)tid_*512;
  const ushort* ei = oei + (size_t)tid_*512;
  const float* uo = user_out + (size_t)b*512;
  const float* io = item_out + (size_t)b*512;
  const int d0 = lane*8;
  float s = 0.f;
  ushort4 a0 = *(const ushort4*)(eu+d0), a1 = *(const ushort4*)(eu+d0+4);
  float4 u0 = *(const float4*)(uo+d0), u1 = *(const float4*)(uo+d0+4);
  s += b2f(a0.x)*u0.x + b2f(a0.y)*u0.y + b2f(a0.z)*u0.z + b2f(a0.w)*u0.w;
  s += b2f(a1.x)*u1.x + b2f(a1.y)*u1.y + b2f(a1.z)*u1.z + b2f(a1.w)*u1.w;
  ushort4 c0 = *(const ushort4*)(ei+d0), c1 = *(const ushort4*)(ei+d0+4);
  float4 i0 = *(const float4*)(io+d0), i1 = *(const float4*)(io+d0+4);
  s += b2f(c0.x)*i0.x + b2f(c0.y)*i0.y + b2f(c0.z)*i0.z + b2f(c0.w)*i0.w;
  s += b2f(c1.x)*i1.x + b2f(c1.y)*i1.y + b2f(c1.z)*i1.z + b2f(c1.w)*i1.w;
  #pragma unroll
  for (int off=32; off>0; off>>=1) s += __shfl_xor(s, off, 64);
  if (lane == 0) {
    out[(size_t)b*NT_ + k] = s;
    float mv, nt;
    if (k < LP_) { mv = (k < pos_l[b]) ? 1.f : 0.f; nt = mv; }
    else         { mv = ((k - LP_) < neg_l[b]) ? 1.f : 0.f; nt = 0.f; }
    out[(size_t)B_*NT_   + (size_t)b*NT_ + k] = mv;
    out[(size_t)2*B_*NT_ + (size_t)b*NT_ + k] = nt;
  }
}

extern "C" void kernel_launch(void* const* d_in, const int* in_sizes, int n_in,
                              void* d_out, int out_size, void* d_ws, size_t ws_size,
                              hipStream_t stream)
{
  const int*   attr      = (const int*)d_in[0];
  const int*   attr_inds = (const int*)d_in[1];
  const float* attr_tf   = (const float*)d_in[2];
  const float* attr_feat = (const float*)d_in[3];
  const int*   attr_lens = (const int*)d_in[4];
  const int*   lens_u    = (const int*)d_in[5];
  const int*   lens_i    = (const int*)d_in[6];
  const int*   user_ids  = (const int*)d_in[7];
  const int*   item_ids  = (const int*)d_in[8];
  const int*   pos_t     = (const int*)d_in[9];
  const int*   pos_l     = (const int*)d_in[10];
  const int*   neg_t     = (const int*)d_in[11];
  const int*   neg_l     = (const int*)d_in[12];
  const float* attr_emb  = (const float*)d_in[13];
  const float* ind_emb   = (const float*)d_in[14];
  const float* user_tab  = (const float*)d_in[15];
  const float* item_tab  = (const float*)d_in[16];
  const float* oeu       = (const float*)d_in[17];
  const float* oei       = (const float*)d_in[18];
  const float* feat_w    = (const float*)d_in[19];
  const float* feat_b    = (const float*)d_in[20];
  const float* Wqkv      = (const float*)d_in[21];
  const float* bqkv      = (const float*)d_in[22];
  const float* Wo        = (const float*)d_in[23];
  const float* bo        = (const float*)d_in[24];
  const float* ln1s      = (const float*)d_in[25];
  const float* ln1b      = (const float*)d_in[26];
  const float* W1        = (const float*)d_in[27];
  const float* b1        = (const float*)d_in[28];
  const float* W2        = (const float*)d_in[29];
  const float* b2        = (const float*)d_in[30];
  const float* ln2s      = (const float*)d_in[31];
  const float* ln2b      = (const float*)d_in[32];

  // ---- ws layout: ints[768] | uo[B,512]f32 | io[B,512]f32 | xb[M,256]bf16 | weights bf16 | oeu_b | oei_b | chunk scratch ----
  int* ioff  = (int*)d_ws;            // off[513]
  int* ccnt  = ioff + 520;
  int* ccntp = ccnt + 64;
  float* ws = (float*)d_ws + 768;
  float* uo = ws;
  float* io = uo + (size_t)B_*512;
  ushort* xb   = (ushort*)(io + (size_t)B_*512);
  ushort* wq_b = xb + (size_t)M_*D_;
  ushort* wo_b = wq_b + (size_t)2*768*256;
  ushort* w1_b = wo_b + (size_t)2*256*256;
  ushort* w2_b = w1_b + (size_t)2*1024*256;
  ushort* oeu_b = w2_b + (size_t)2*256*1024;
  ushort* oei_b = oeu_b + (size_t)V_*512;
  float* scratch = (float*)(oei_b + (size_t)V_*512);

  const size_t fixed_floats = 768 + (size_t)B_*1024 + (size_t)M_*(D_/2) + 786432 + (size_t)V_*512;
  int Bc = 8;
  for (int cand = 512; cand >= 8; cand >>= 1) {
    size_t need = (fixed_floats + (size_t)cand*L_*512) * sizeof(float);
    if (need <= ws_size) { Bc = cand; break; }
  }
  const int nchunks = B_ / Bc;
  const size_t Mc = (size_t)Bc * L_;

  float* out = (float*)d_out;

  k_prefix<<<1, 512, 0, stream>>>(attr_lens, ioff, ccnt, ccntp, Bc, nchunks);
  k_f2b4<<<768, 256, 0, stream>>>(Wqkv, Wo, W1, W2, wq_b, wo_b, w1_b, w2_b);
  k_f2b<<<(V_*512)/2048, 256, 0, stream>>>(oeu, oeu_b);
  k_f2b<<<(V_*512)/2048, 256, 0, stream>>>(oei, oei_b);
  k_embed<<<M_*64/256, 256, 0, stream>>>(attr, attr_inds, attr_lens, ioff, attr_emb, ind_emb, xb);

  for (int l=0; l<NL_; ++l) {
    const float* bqkv_l = bqkv + (size_t)l*768;
    const float* bo_l   = bo   + (size_t)l*D_;
    const float* b1_l   = b1   + (size_t)l*FF_;
    const float* b2_l   = b2   + (size_t)l*D_;
    for (int c=0; c<nchunks; ++c) {
      const int* offc = ioff + c*Bc;
      const int* cntp = ccntp + c;
      const int* cnt  = ccnt + c;
      ushort* qkv_b = (ushort*)scratch;                 // [Mc,768] bf16
      ushort* ctx_b = (ushort*)(scratch + Mc*384);      // [Mc,256] bf16

      k_gemm_mfma<1,0><<<dim3(768/128, Mc/128), 256, 0, stream>>>(
          xb, offc, cntp, wq_b + (size_t)l*768*256, bqkv_l, qkv_b, 768, 256);
      k_attn_mfma<<<Bc*H_, 256, 0, stream>>>(qkv_b, ctx_b, offc);
      k_gemm_ln<<<Mc/128, 512, 0, stream>>>(
          ctx_b, cntp, cnt, offc, wo_b + (size_t)l*256*256, bo_l,
          ln1s + (size_t)l*D_, ln1b + (size_t)l*D_, xb, 256);
      k_ffn<<<Mc/64, 512, 0, stream>>>(
          cntp, cnt, offc, w1_b + (size_t)l*1024*256, b1_l,
          w2_b + (size_t)l*256*1024, b2_l,
          ln2s + (size_t)l*D_, ln2b + (size_t)l*D_, xb);
    }
  }
  k_pool<<<B_, 256, 0, stream>>>(xb, ioff, attr_tf, attr_feat, lens_u, lens_i, user_ids, item_ids,
                                 user_tab, item_tab, feat_w, feat_b, uo, io);
  k_logits<<<B_*NT_/4, 256, 0, stream>>>(pos_t, neg_t, pos_l, neg_l, oeu_b, oei_b, uo, io, out);
}